// Round 5
// baseline (651.574 us; speedup 1.0000x reference)
//
#include <hip/hip_runtime.h>

#define N_NODES 50000
#define N_EDGES 800000
#define N_GRAPHS 256
#define F 100  // hidden dim

#define SCAN_PAD 50176      // 1024 threads * 49

#define PART_SZ 6250        // 8 dst partitions * 6250 = 50000
#define FILL_CHUNK 2048
#define HIST_BLOCKS 3128    // 391 chunks * 8 partitions

#define AST 264             // fused-layer A-tile row stride in shorts

typedef __attribute__((ext_vector_type(8))) short bf16x8;
typedef __attribute__((ext_vector_type(4))) float f32x4;
typedef unsigned short ushort_t;
typedef unsigned int uint_t;

__device__ inline ushort_t f2bf(float f) {  // RNE float->bf16
  uint_t u = __float_as_uint(f);
  uint_t r = (u + 0x7fffu + ((u >> 16) & 1u)) >> 16;
  return (ushort_t)r;
}

// ---------------- D1: merged packing + cnt zeroing ----------------
// blocks 0..207: Wp1 [208][384]; 208..719: Wf [4][128][256]; 720..768: zero cnt.

__global__ __launch_bounds__(256) void pack_all(
    const float* __restrict__ w1_rel, const float* __restrict__ w1_root,
    const float* __restrict__ w_rel, const float* __restrict__ w_root,
    ushort_t* __restrict__ Wp1, ushort_t* __restrict__ Wf, int* __restrict__ cnt) {
  int b = blockIdx.x;
  int tid = threadIdx.x;
  if (b < 208) {
    int row = b;
    for (int k = tid; k < 384; k += 256) {
      float v = 0.f;
      if (k < 336) {
        if (row < 100) v = w1_rel[row * 336 + k];
        else if (row < 200) v = w1_root[(row - 100) * 336 + k];
      }
      Wp1[(size_t)row * 384 + k] = f2bf(v);
    }
  } else if (b < 720) {
    int rowl = b - 208;           // l*128 + row
    int l = rowl >> 7, row = rowl & 127;
    int k = tid;                  // 0..255
    float v = 0.f;
    if (row < 100) {
      if (k < 100) v = w_rel[((size_t)l * 100 + row) * 100 + k];
      else if (k >= 128 && k < 228) v = w_root[((size_t)l * 100 + row) * 100 + (k - 128)];
    }
    Wf[(size_t)rowl * 256 + k] = f2bf(v);
  } else {
    int z = b - 720;              // 0..48, each zeroes 1024 ints
    *(int4*)(cnt + (size_t)z * 1024 + tid * 4) = make_int4(0, 0, 0, 0);
  }
}

// ---------------- D2: hist (blocks 0..3127) + layer-1 conv (blocks 3128..3639) ----------------
// Independent work co-dispatched so conv1 (~52us) hides the histogram (~20us).
// conv part: R2-verified swapped-operand reg GEMM; per-lane W loads from L2 (53KB panel),
// on-the-fly f32->bf16 A-fragments, ushort4 coalesced stores into ZP (Zrel|Zroot+b1).

__global__ __launch_bounds__(256) void hist_conv(
    const int* __restrict__ dst, int* __restrict__ cnt, int E,
    const float* __restrict__ x, const ushort_t* __restrict__ Wp1,
    const float* __restrict__ b1, ushort_t* __restrict__ ZP) {
  int tid = threadIdx.x;
  if (blockIdx.x < HIST_BLOCKS) {
    int part = blockIdx.x & 7;
    int lo = part * PART_SZ, hi = lo + PART_SZ;
    int base = (blockIdx.x >> 3) * FILL_CHUNK;
    int end = base + FILL_CHUNK; if (end > E) end = E;
    for (int i = base + tid; i < end; i += 256) {
      int d = dst[i];
      if (d >= lo && d < hi) atomicAdd(&cnt[d], 1);
    }
    return;
  }
  int cb = blockIdx.x - HIST_BLOCKS;    // 0..511
  int w = tid >> 6, lane = tid & 63, q = lane >> 4, m16 = lane & 15;
  int gw = cb * 4 + w;                  // 2048 conv waves
  for (int tile = gw; tile < 3125; tile += 2048) {
    int node = tile * 16 + m16;
    const float* xrow = x + (size_t)node * 336;
    f32x4 acc[13];
#pragma unroll
    for (int b = 0; b < 13; ++b) acc[b] = (f32x4)0.f;
#pragma unroll
    for (int s = 0; s < 11; ++s) {      // k 352..383 all-zero: Wp1 zero-padded
      int k0 = s * 32 + q * 8;
      bf16x8 af = (bf16x8)0;
      if (k0 < 336) {
        float4 f0 = *(const float4*)(xrow + k0);
        float4 f1 = *(const float4*)(xrow + k0 + 4);
        af[0] = (short)f2bf(f0.x); af[1] = (short)f2bf(f0.y);
        af[2] = (short)f2bf(f0.z); af[3] = (short)f2bf(f0.w);
        af[4] = (short)f2bf(f1.x); af[5] = (short)f2bf(f1.y);
        af[6] = (short)f2bf(f1.z); af[7] = (short)f2bf(f1.w);
      }
#pragma unroll
      for (int b = 0; b < 13; ++b) {
        bf16x8 wf = *(const bf16x8*)(Wp1 + (size_t)(b * 16 + m16) * 384 + s * 32 + q * 8);
        acc[b] = __builtin_amdgcn_mfma_f32_16x16x32_bf16(wf, af, acc[b], 0, 0, 0);
      }
    }
    size_t zbase = (size_t)node * 256;
#pragma unroll
    for (int b = 0; b < 13; ++b) {
      int n0 = b * 16 + q * 4;
      if (n0 < 100) {
        ushort4 v;
        v.x = f2bf(acc[b][0]); v.y = f2bf(acc[b][1]);
        v.z = f2bf(acc[b][2]); v.w = f2bf(acc[b][3]);
        *(ushort4*)(ZP + zbase + n0) = v;
      } else if (n0 < 200) {
        float4 bb = *(const float4*)(b1 + n0 - 100);
        ushort4 v;
        v.x = f2bf(acc[b][0] + bb.x); v.y = f2bf(acc[b][1] + bb.y);
        v.z = f2bf(acc[b][2] + bb.z); v.w = f2bf(acc[b][3] + bb.w);
        *(ushort4*)(ZP + zbase + n0 + 28) = v;  // Zroot cols 128..227
      }
    }
  }
}

// ---------------- D3: single-dispatch scan (replaces scan1/scan2/scan3) ----------------

__global__ __launch_bounds__(1024) void scan_all(const int* __restrict__ cnt,
                                                 int* __restrict__ offs,
                                                 int* __restrict__ cursor) {
  __shared__ int part[1024];
  int t = threadIdx.x;
  int base = t * 49;
  int s = 0;
#pragma unroll 7
  for (int i = 0; i < 49; ++i) s += cnt[base + i];
  part[t] = s;
  __syncthreads();
  for (int off = 1; off < 1024; off <<= 1) {
    int u = (t >= off) ? part[t - off] : 0;
    __syncthreads();
    part[t] += u;
    __syncthreads();
  }
  int run = part[t] - s;  // exclusive prefix of this thread's chunk
#pragma unroll 7
  for (int i = 0; i < 49; ++i) {
    int idx = base + i;
    int c = cnt[idx];
    if (idx <= N_NODES) { offs[idx] = run; cursor[idx] = run; }
    run += c;
  }
}

// ---------------- D4: fill ----------------

__global__ __launch_bounds__(256) void fill_kernel(const int* __restrict__ src,
                                                   const int* __restrict__ dst,
                                                   int* __restrict__ cursor,
                                                   int* __restrict__ csr_src, int E) {
  int part = blockIdx.x & 7;
  int lo = part * PART_SZ, hi = lo + PART_SZ;
  int base = (blockIdx.x >> 3) * FILL_CHUNK;
  int end = base + FILL_CHUNK; if (end > E) end = E;
  for (int i = base + threadIdx.x; i < end; i += 256) {
    int d = dst[i];
    if (d >= lo && d < hi) {
      int p = atomicAdd(&cursor[d], 1);
      csr_src[p] = src[i];
    }
  }
}

// ---------------- D5: gather1 (persistent): H1[i] = relu(Zroot[i] + sum Zrel[src]) ----------------

__global__ __launch_bounds__(256) void gather_bf16(
    const ushort_t* __restrict__ ZP,
    const int* __restrict__ offs, const int* __restrict__ csr,
    ushort_t* __restrict__ H) {
  int lane = threadIdx.x & 63;
  int off = (lane < 50 ? lane : 49) * 2;  // ushort offset within 100-col payload
  for (int nb = blockIdx.x; nb < N_NODES / 4; nb += gridDim.x) {
    int node = nb * 4 + (threadIdx.x >> 6);
    node = __builtin_amdgcn_readfirstlane(node);  // wave-uniform -> scalar offs loads

    uint_t z = *(const uint_t*)(ZP + (size_t)node * 256 + 128 + off);  // Zroot half
    float p0[8], p1[8];
#pragma unroll
    for (int u = 0; u < 8; ++u) { p0[u] = 0.f; p1[u] = 0.f; }
    p0[0] = __uint_as_float(z << 16);
    p1[0] = __uint_as_float(z & 0xffff0000u);

    int s = offs[node], e = offs[node + 1];
    for (int j = s; j < e; j += 64) {
      int take = e - j; if (take > 64) take = 64;
      int vidx = (lane < take) ? csr[j + lane] : 0;  // one coalesced vector load
      int u = 0;
      for (; u + 8 <= take; u += 8) {
        uint_t zz[8];
#pragma unroll
        for (int t = 0; t < 8; ++t) {
          int idx = __builtin_amdgcn_readlane(vidx, u + t);
          zz[t] = *(const uint_t*)(ZP + (size_t)idx * 256 + off);
        }
#pragma unroll
        for (int t = 0; t < 8; ++t) {
          p0[t] += __uint_as_float(zz[t] << 16);
          p1[t] += __uint_as_float(zz[t] & 0xffff0000u);
        }
      }
      int cnt2 = take - u;  // 0..7, wave-uniform
      if (cnt2 > 0) {
        uint_t zz[7];
#pragma unroll
        for (int t = 0; t < 7; ++t) {
          if (t < cnt2) {
            int idx = __builtin_amdgcn_readlane(vidx, u + t);
            zz[t] = *(const uint_t*)(ZP + (size_t)idx * 256 + off);
          }
        }
#pragma unroll
        for (int t = 0; t < 7; ++t) {
          if (t < cnt2) {
            p0[t] += __uint_as_float(zz[t] << 16);
            p1[t] += __uint_as_float(zz[t] & 0xffff0000u);
          }
        }
      }
    }
    float a0 = ((p0[0] + p0[1]) + (p0[2] + p0[3])) + ((p0[4] + p0[5]) + (p0[6] + p0[7]));
    float a1 = ((p1[0] + p1[1]) + (p1[2] + p1[3])) + ((p1[4] + p1[5]) + (p1[6] + p1[7]));
    a0 = fmaxf(a0, 0.f);
    a1 = fmaxf(a1, 0.f);
    uint_t outp = (uint_t)f2bf(a0) | ((uint_t)f2bf(a1) << 16);
    if (lane >= 50) outp = 0u;  // pad cols 100..127 = 0
    *(uint_t*)(H + (size_t)node * 128 + lane * 2) = outp;
  }
}

// ---------------- D6-9: fused gather-first + GEMM (persistent, R3-verified body) ----------------
// out_i = relu([Wrel|Wroot] @ [sum_j h_j ; h_i] + b). 512 blocks x 8 waves grid-stride over
// 3125 16-node tiles; wave w gathers 2 nodes into A-tile rows, barrier, computes output
// frag b=w (8 MFMA, W-frags preloaded ONCE per kernel); bias+relu; ushort4 store.

__global__ __launch_bounds__(512) void fused_layer(
    const ushort_t* __restrict__ Hin,
    const ushort_t* __restrict__ Wf,    // [128][256] bf16
    const float* __restrict__ bias,     // [100]
    const int* __restrict__ offs, const int* __restrict__ csr,
    ushort_t* __restrict__ Hout) {
  __shared__ short alds[16 * AST];

  int tid = threadIdx.x;
  int w = tid >> 6, lane = tid & 63, q = lane >> 4, m16 = lane & 15;

  bf16x8 wreg[8];
#pragma unroll
  for (int s = 0; s < 8; ++s)
    wreg[s] = *(const bf16x8*)(Wf + (size_t)(w * 16 + m16) * 256 + s * 32 + q * 8);
  int n0 = w * 16 + q * 4;
  float4 bb = make_float4(0.f, 0.f, 0.f, 0.f);
  if (n0 < 100) bb = *(const float4*)(bias + n0);

  for (int tile = blockIdx.x; tile < 3125; tile += gridDim.x) {
    for (int sub = 0; sub < 2; ++sub) {
      int row = w * 2 + sub;
      int node = tile * 16 + row;
      node = __builtin_amdgcn_readfirstlane(node);
      uint_t hv = *(const uint_t*)(Hin + (size_t)node * 128 + lane * 2);
      *(uint_t*)&alds[row * AST + 128 + lane * 2] = hv;   // own-h, A cols 128..255
      int off = (lane < 50 ? lane : 49) * 2;
      float p0[8], p1[8];
#pragma unroll
      for (int u = 0; u < 8; ++u) { p0[u] = 0.f; p1[u] = 0.f; }
      int s = offs[node], e = offs[node + 1];
      for (int j = s; j < e; j += 64) {
        int take = e - j; if (take > 64) take = 64;
        int vidx = (lane < take) ? csr[j + lane] : 0;
        int u = 0;
        for (; u + 8 <= take; u += 8) {
          uint_t zz[8];
#pragma unroll
          for (int t = 0; t < 8; ++t) {
            int idx = __builtin_amdgcn_readlane(vidx, u + t);
            zz[t] = *(const uint_t*)(Hin + (size_t)idx * 128 + off);
          }
#pragma unroll
          for (int t = 0; t < 8; ++t) {
            p0[t] += __uint_as_float(zz[t] << 16);
            p1[t] += __uint_as_float(zz[t] & 0xffff0000u);
          }
        }
        int cnt2 = take - u;
        if (cnt2 > 0) {
          uint_t zz[7];
#pragma unroll
          for (int t = 0; t < 7; ++t) {
            if (t < cnt2) {
              int idx = __builtin_amdgcn_readlane(vidx, u + t);
              zz[t] = *(const uint_t*)(Hin + (size_t)idx * 128 + off);
            }
          }
#pragma unroll
          for (int t = 0; t < 7; ++t) {
            if (t < cnt2) {
              p0[t] += __uint_as_float(zz[t] << 16);
              p1[t] += __uint_as_float(zz[t] & 0xffff0000u);
            }
          }
        }
      }
      float a0 = ((p0[0] + p0[1]) + (p0[2] + p0[3])) + ((p0[4] + p0[5]) + (p0[6] + p0[7]));
      float a1 = ((p1[0] + p1[1]) + (p1[2] + p1[3])) + ((p1[4] + p1[5]) + (p1[6] + p1[7]));
      uint_t outp = (uint_t)f2bf(a0) | ((uint_t)f2bf(a1) << 16);
      if (lane >= 50) outp = 0u;   // A cols 100..127 = 0
      *(uint_t*)&alds[row * AST + lane * 2] = outp;
    }
    __syncthreads();
    f32x4 acc = (f32x4)0.f;
#pragma unroll
    for (int s = 0; s < 8; ++s) {
      bf16x8 af = *(const bf16x8*)&alds[m16 * AST + s * 32 + q * 8];
      acc = __builtin_amdgcn_mfma_f32_16x16x32_bf16(wreg[s], af, acc, 0, 0, 0);
    }
    int nodeo = tile * 16 + m16;
    ushort4 v;
    v.x = f2bf(fmaxf(acc[0] + bb.x, 0.f));
    v.y = f2bf(fmaxf(acc[1] + bb.y, 0.f));
    v.z = f2bf(fmaxf(acc[2] + bb.z, 0.f));
    v.w = f2bf(fmaxf(acc[3] + bb.w, 0.f));
    *(ushort4*)(Hout + (size_t)nodeo * 128 + n0) = v;  // n0<128: pad cols get 0
    __syncthreads();   // alds reused next tile
  }
}

// ---------------- D10: fused pool + MLP head ----------------

__global__ __launch_bounds__(1024) void pool_mlp(
    const ushort_t* __restrict__ H, const int* __restrict__ batch,
    const float* __restrict__ lw1, const float* __restrict__ lb1,
    const float* __restrict__ lw2, const float* __restrict__ lb2,
    const float* __restrict__ lw3, const float* __restrict__ lb3,
    float* __restrict__ out) {
  int g = blockIdx.x;
  int t = threadIdx.x;
  int lo = 0, hi = N_NODES;
  while (lo < hi) { int mid = (lo + hi) >> 1; if (batch[mid] < g) lo = mid + 1; else hi = mid; }
  int s = lo;
  hi = N_NODES;
  while (lo < hi) { int mid = (lo + hi) >> 1; if (batch[mid] <= g) lo = mid + 1; else hi = mid; }
  int e = lo;

  int row = t >> 6;      // 16 node-rows
  int lane = t & 63;
  int off = (lane < 50 ? lane : 49) * 2;
  float a0 = 0.f, a1 = 0.f;
  for (int n = s + row; n < e; n += 16) {
    uint_t z = *(const uint_t*)(H + (size_t)n * 128 + off);
    a0 += __uint_as_float(z << 16);
    a1 += __uint_as_float(z & 0xffff0000u);
  }
  __shared__ float sh[16][104];
  __shared__ float r0[F], r1[F], r2[F];
  if (lane < 50) { sh[row][lane * 2] = a0; sh[row][lane * 2 + 1] = a1; }
  __syncthreads();
  if (t < F) {
    float acc = 0.f;
#pragma unroll
    for (int r = 0; r < 16; ++r) acc += sh[r][t];
    int cnt = e - s;
    float d = (cnt > 0) ? (float)cnt : 1.f;
    r0[t] = acc / d;
  }
  __syncthreads();
  if (t < F) {
    float sv = lb1[t];
    for (int k = 0; k < F; ++k) sv += r0[k] * lw1[t * F + k];
    r1[t] = fmaxf(sv, 0.f);
  }
  __syncthreads();
  if (t < F) {
    float sv = lb2[t];
    for (int k = 0; k < F; ++k) sv += r1[k] * lw2[t * F + k];
    r2[t] = fmaxf(sv, 0.f);
  }
  __syncthreads();
  if (t < 29) {
    float sv = lb3[t];
    for (int k = 0; k < F; ++k) sv += r2[k] * lw3[t * F + k];
    out[g * 29 + t] = sv;
  }
}

// ---------------- launch ------------------------------------------------------------------------

extern "C" void kernel_launch(void* const* d_in, const int* in_sizes, int n_in,
                              void* d_out, int out_size, void* d_ws, size_t ws_size,
                              hipStream_t stream) {
  const float* x       = (const float*)d_in[0];
  const int*   ei      = (const int*)d_in[1];
  const int*   batch   = (const int*)d_in[2];
  const float* w1_rel  = (const float*)d_in[3];
  const float* w1_root = (const float*)d_in[4];
  const float* b1      = (const float*)d_in[5];
  const float* w_rel   = (const float*)d_in[6];
  const float* w_root  = (const float*)d_in[7];
  const float* bvec    = (const float*)d_in[8];
  const float* lw1     = (const float*)d_in[9];
  const float* lb1     = (const float*)d_in[10];
  const float* lw2     = (const float*)d_in[11];
  const float* lb2     = (const float*)d_in[12];
  const float* lw3     = (const float*)d_in[13];
  const float* lb3     = (const float*)d_in[14];
  float* out = (float*)d_out;

  // workspace layout
  char* ws = (char*)d_ws;
  size_t o = 0;
  auto alloc = [&](size_t bytes) { void* p = ws + o; o = (o + bytes + 511) & ~(size_t)511; return p; };
  ushort_t* H1   = (ushort_t*)alloc((size_t)N_NODES * 128 * 2);   // 12.8 MB
  ushort_t* H2   = (ushort_t*)alloc((size_t)N_NODES * 128 * 2);   // 12.8 MB
  ushort_t* ZP   = (ushort_t*)alloc((size_t)N_NODES * 256 * 2);   // 25.6 MB
  ushort_t* Wp1  = (ushort_t*)alloc((size_t)208 * 384 * 2);
  ushort_t* Wf   = (ushort_t*)alloc((size_t)4 * 128 * 256 * 2);
  int* cnt    = (int*)alloc((size_t)SCAN_PAD * 4);
  int* offs   = (int*)alloc((size_t)(N_NODES + 1) * 4);
  int* cursor = (int*)alloc((size_t)(N_NODES + 1) * 4);
  int* csr    = (int*)alloc((size_t)N_EDGES * 4);

  const int E = N_EDGES;
  const int* srcv = ei;
  const int* dstv = ei + E;

  // 9 dispatches total (was 16).
  pack_all<<<769, 256, 0, stream>>>(w1_rel, w1_root, w_rel, w_root, Wp1, Wf, cnt);
  hist_conv<<<HIST_BLOCKS + 512, 256, 0, stream>>>(dstv, cnt, E, x, Wp1, b1, ZP);
  scan_all<<<1, 1024, 0, stream>>>(cnt, offs, cursor);
  fill_kernel<<<HIST_BLOCKS, 256, 0, stream>>>(srcv, dstv, cursor, csr, E);
  gather_bf16<<<1024, 256, 0, stream>>>(ZP, offs, csr, H1);

  const ushort_t* hin = H1;
  ushort_t* hout = H2;
  for (int l = 0; l < 4; ++l) {
    fused_layer<<<512, 512, 0, stream>>>(hin, Wf + (size_t)l * 128 * 256,
                                         bvec + (size_t)l * F, offs, csr, hout);
    const ushort_t* tmp = hout; hout = (ushort_t*)hin; hin = tmp;
  }
  // after 4 swaps hin == H1
  pool_mlp<<<N_GRAPHS, 1024, 0, stream>>>(hin, batch, lw1, lb1, lw2, lb2, lw3, lb3, out);
}

// Round 6
// 576.112 us; speedup vs baseline: 1.1310x; 1.1310x over previous
//
#include <hip/hip_runtime.h>

#define N_NODES 50000
#define N_EDGES 800000
#define N_GRAPHS 256
#define F 100  // hidden dim

#define SCAN_PAD 50176      // 1024 threads * 49

#define PART_SZ 6250        // 8 dst partitions * 6250 = 50000
#define FILL_CHUNK 2048
#define HIST_BLOCKS 3128    // 391 chunks * 8 partitions

#define SROW 72             // conv1 LDS row stride in shorts
#define EPS 264             // conv1 epilogue LDS row stride in shorts
#define AST 264             // fused-layer A-tile row stride in shorts

#define SENT N_NODES        // sentinel row index (zeroed) for CSR padding
#define CSR_CAP 1155072     // 282*4096 ints >= 800000 + 50000*7 + 64 overread slack

typedef __attribute__((ext_vector_type(8))) short bf16x8;
typedef __attribute__((ext_vector_type(4))) float f32x4;
typedef unsigned short ushort_t;
typedef unsigned int uint_t;

__device__ inline ushort_t f2bf(float f) {  // RNE float->bf16
  uint_t u = __float_as_uint(f);
  uint_t r = (u + 0x7fffu + ((u >> 16) & 1u)) >> 16;
  return (ushort_t)r;
}

// ---------------- D1: merged packing + cnt zeroing + csr sentinel prefill ----------------
// blocks 0..207: Wp1; 208..719: Wf; 720..768: zero cnt; 769..1050: csr=SENT; 1051: zero
// sentinel rows of ZP/H1/H2 (row 50000 stays zero: gather/fused only write nodes<50000).

__global__ __launch_bounds__(256) void pack_all(
    const float* __restrict__ w1_rel, const float* __restrict__ w1_root,
    const float* __restrict__ w_rel, const float* __restrict__ w_root,
    ushort_t* __restrict__ Wp1, ushort_t* __restrict__ Wf, int* __restrict__ cnt,
    int* __restrict__ csr, ushort_t* __restrict__ ZP,
    ushort_t* __restrict__ H1, ushort_t* __restrict__ H2) {
  int b = blockIdx.x;
  int tid = threadIdx.x;
  if (b < 208) {
    int row = b;
    for (int k = tid; k < 384; k += 256) {
      float v = 0.f;
      if (k < 336) {
        if (row < 100) v = w1_rel[row * 336 + k];
        else if (row < 200) v = w1_root[(row - 100) * 336 + k];
      }
      Wp1[(size_t)row * 384 + k] = f2bf(v);
    }
  } else if (b < 720) {
    int rowl = b - 208;           // l*128 + row
    int l = rowl >> 7, row = rowl & 127;
    int k = tid;                  // 0..255
    float v = 0.f;
    if (row < 100) {
      if (k < 100) v = w_rel[((size_t)l * 100 + row) * 100 + k];
      else if (k >= 128 && k < 228) v = w_root[((size_t)l * 100 + row) * 100 + (k - 128)];
    }
    Wf[(size_t)rowl * 256 + k] = f2bf(v);
  } else if (b < 769) {
    int z = b - 720;              // 0..48, each zeroes 1024 ints
    *(int4*)(cnt + (size_t)z * 1024 + tid * 4) = make_int4(0, 0, 0, 0);
  } else if (b < 1051) {
    // csr sentinel prefill: 282 blocks * 4096 ints
    int i0 = (b - 769) * 4096 + tid * 16;
    int4 sv = make_int4(SENT, SENT, SENT, SENT);
    *(int4*)(csr + i0) = sv; *(int4*)(csr + i0 + 4) = sv;
    *(int4*)(csr + i0 + 8) = sv; *(int4*)(csr + i0 + 12) = sv;
  } else {
    uint4 z4 = make_uint4(0u, 0u, 0u, 0u);
    if (tid < 32)      *(uint4*)(ZP + (size_t)SENT * 256 + tid * 8) = z4;
    else if (tid < 48) *(uint4*)(H1 + (size_t)SENT * 128 + (tid - 32) * 8) = z4;
    else if (tid < 64) *(uint4*)(H2 + (size_t)SENT * 128 + (tid - 48) * 8) = z4;
  }
}

// ---------------- D2: hist ----------------

__global__ __launch_bounds__(256) void hist_kernel(const int* __restrict__ dst,
                                                   int* __restrict__ cnt, int E) {
  int part = blockIdx.x & 7;
  int lo = part * PART_SZ, hi = lo + PART_SZ;
  int base = (blockIdx.x >> 3) * FILL_CHUNK;
  int end = base + FILL_CHUNK; if (end > E) end = E;
  for (int i = base + threadIdx.x; i < end; i += 256) {
    int d = dst[i];
    if (d >= lo && d < hi) atomicAdd(&cnt[d], 1);
  }
}

// ---------------- D3: single-block scan with 8-padded slots ----------------
// R6: each node's csr slot rounded up to a multiple of 8; pads hold SENT (prefilled)
// -> gather inner loop is uniform groups of 8, no remainder ladder, no masked loads.

__global__ __launch_bounds__(1024) void scan_all(const int* __restrict__ cnt,
                                                 int* __restrict__ offs,
                                                 int* __restrict__ cursor) {
  __shared__ int part[1024];
  int t = threadIdx.x;
  int base = t * 49;
  int s = 0;
  for (int i = 0; i < 49; ++i) s += (cnt[base + i] + 7) & ~7;
  part[t] = s;
  __syncthreads();
  for (int off = 1; off < 1024; off <<= 1) {
    int u = (t >= off) ? part[t - off] : 0;
    __syncthreads();
    part[t] += u;
    __syncthreads();
  }
  int run = part[t] - s;  // exclusive prefix of this thread's chunk (padded)
  for (int i = 0; i < 49; ++i) {
    int idx = base + i;
    int slot = (cnt[idx] + 7) & ~7;
    if (idx <= N_NODES) { offs[idx] = run; cursor[idx] = run; }
    run += slot;
  }
}

// ---------------- D4: fill (real edges into [offs, offs+cnt); pads stay SENT) ----------------

__global__ __launch_bounds__(256) void fill_kernel(const int* __restrict__ src,
                                                   const int* __restrict__ dst,
                                                   int* __restrict__ cursor,
                                                   int* __restrict__ csr_src, int E) {
  int part = blockIdx.x & 7;
  int lo = part * PART_SZ, hi = lo + PART_SZ;
  int base = (blockIdx.x >> 3) * FILL_CHUNK;
  int end = base + FILL_CHUNK; if (end > E) end = E;
  for (int i = base + threadIdx.x; i < end; i += 256) {
    int d = dst[i];
    if (d >= lo && d < hi) {
      int p = atomicAdd(&cursor[d], 1);
      csr_src[p] = src[i];
    }
  }
}

// ---------------- D5: layer-1 conv (R1-verified: LDS staging + LDS-transpose epilogue) ----------
// R5 lesson: the no-LDS variant scatters 8B stores (WRITE 144MB, RFO) and row-scatters
// reads (FETCH 122MB) -> 205us. This form: FETCH 35MB, WRITE 25MB, 52us. Keep.

template <bool AF32>
__global__ __launch_bounds__(256) void conv_mfma(
    const void* __restrict__ Aptr, const ushort_t* __restrict__ Wp,
    const float* __restrict__ bias,
    ushort_t* __restrict__ ZP, int Kp) {
  __shared__ short smem[64 * SROW + 208 * SROW];
  __shared__ float bias_s[104];
  short* alds = smem;
  short* blds = smem + 64 * SROW;

  int tid = threadIdx.x;
  int n0 = blockIdx.x * 64;
  if (tid < 100) bias_s[tid] = bias[tid];

  f32x4 acc[13];
#pragma unroll
  for (int b = 0; b < 13; ++b) acc[b] = (f32x4)0.f;

  int w = tid >> 6, lane = tid & 63, q = lane >> 4, m16 = lane & 15;

  int ar[2], aq[2];
#pragma unroll
  for (int u = 0; u < 2; ++u) { int c = tid + u * 256; ar[u] = c >> 3; aq[u] = c & 7; }

  bf16x8 areg[2], breg[7];

  auto load_chunk = [&](int k0) {
#pragma unroll
    for (int u = 0; u < 2; ++u) {
      int node = n0 + ar[u];
      int k = k0 + aq[u] * 8;
      bf16x8 val = (bf16x8)0;
      if (AF32) {
        if (node < N_NODES && k < 336) {
          const float* p = (const float*)Aptr + (size_t)node * 336 + k;
          float4 f0 = *(const float4*)p;
          float4 f1 = *(const float4*)(p + 4);
          val[0] = (short)f2bf(f0.x); val[1] = (short)f2bf(f0.y);
          val[2] = (short)f2bf(f0.z); val[3] = (short)f2bf(f0.w);
          val[4] = (short)f2bf(f1.x); val[5] = (short)f2bf(f1.y);
          val[6] = (short)f2bf(f1.z); val[7] = (short)f2bf(f1.w);
        }
      } else {
        if (node < N_NODES)
          val = *(const bf16x8*)((const short*)Aptr + (size_t)node * 128 + k);
      }
      areg[u] = val;
    }
#pragma unroll
    for (int u = 0; u < 7; ++u) {
      int c = tid + u * 256;
      if (c < 1664) {
        int r = c >> 3, qq = c & 7;
        breg[u] = *(const bf16x8*)((const short*)Wp + (size_t)r * Kp + k0 + qq * 8);
      }
    }
  };

  load_chunk(0);

  for (int k0 = 0; k0 < Kp; k0 += 64) {
#pragma unroll
    for (int u = 0; u < 2; ++u)
      *(bf16x8*)&alds[ar[u] * SROW + aq[u] * 8] = areg[u];
#pragma unroll
    for (int u = 0; u < 7; ++u) {
      int c = tid + u * 256;
      if (c < 1664) {
        int r = c >> 3, qq = c & 7;
        *(bf16x8*)&blds[r * SROW + qq * 8] = breg[u];
      }
    }
    __syncthreads();
    if (k0 + 64 < Kp) load_chunk(k0 + 64);
#pragma unroll
    for (int s = 0; s < 2; ++s) {
      bf16x8 a = *(const bf16x8*)&alds[(w * 16 + m16) * SROW + s * 32 + q * 8];
#pragma unroll
      for (int b = 0; b < 13; ++b) {
        bf16x8 bf = *(const bf16x8*)&blds[(b * 16 + m16) * SROW + s * 32 + q * 8];
        acc[b] = __builtin_amdgcn_mfma_f32_16x16x32_bf16(a, bf, acc[b], 0, 0, 0);
      }
    }
    __syncthreads();
  }

  // epilogue: transpose through LDS, full-line coalesced stores
  short* ep = smem;
#pragma unroll
  for (int b = 0; b < 13; ++b) {
    int n = b * 16 + m16;
    if (n < 200) {
      int c = (n < 100) ? n : (n + 28);
      float add = (n < 100) ? 0.f : bias_s[(n - 100) & 127];
#pragma unroll
      for (int r = 0; r < 4; ++r) {
        int row = w * 16 + q * 4 + r;
        ep[row * EPS + c] = (short)f2bf(acc[b][r] + add);
      }
    }
  }
  __syncthreads();
#pragma unroll
  for (int j = 0; j < 8; ++j) {
    int i = tid + j * 256;
    int row = i >> 5, c16 = i & 31;
    int node = n0 + row;
    if (node < N_NODES) {
      *(uint4*)(ZP + (size_t)node * 256 + c16 * 8) =
          *(const uint4*)&ep[row * EPS + c16 * 8];
    }
  }
}

// ---------------- D6: gather1 (R6: double-buffered load groups, padded slots) ----------------
// Old inner loop serialized: issue 8, vmcnt(0), add, repeat -> deg-16 node = 2 serial
// round trips. Now group g+1's loads issue BEFORE consuming group g.

__global__ __launch_bounds__(256) void gather_bf16(
    const ushort_t* __restrict__ ZP,
    const int* __restrict__ offs, const int* __restrict__ csr,
    ushort_t* __restrict__ H) {
  int lane = threadIdx.x & 63;
  int off = (lane < 50 ? lane : 49) * 2;
  int node = blockIdx.x * 4 + (threadIdx.x >> 6);
  node = __builtin_amdgcn_readfirstlane(node);

  uint_t z = *(const uint_t*)(ZP + (size_t)node * 256 + 128 + off);  // Zroot half
  float p0[8], p1[8];
#pragma unroll
  for (int u = 0; u < 8; ++u) { p0[u] = 0.f; p1[u] = 0.f; }
  p0[0] = __uint_as_float(z << 16);
  p1[0] = __uint_as_float(z & 0xffff0000u);

  int s = offs[node], e = offs[node + 1];   // e-s multiple of 8 (pads -> SENT zero row)
  uint_t zA[8], zB[8];
  for (int j = s; j < e; j += 64) {
    int rem = e - j;
    int ng = (rem > 64 ? 64 : rem) >> 3;    // 1..8 uniform groups
    int vidx = csr[j + lane];               // unconditional coalesced load (cap has slack)
    auto loadA = [&](int g) {
#pragma unroll
      for (int t = 0; t < 8; ++t) {
        int idx = __builtin_amdgcn_readlane(vidx, g * 8 + t);
        zA[t] = *(const uint_t*)(ZP + (size_t)idx * 256 + off);
      }
    };
    auto loadB = [&](int g) {
#pragma unroll
      for (int t = 0; t < 8; ++t) {
        int idx = __builtin_amdgcn_readlane(vidx, g * 8 + t);
        zB[t] = *(const uint_t*)(ZP + (size_t)idx * 256 + off);
      }
    };
    auto consA = [&]() {
#pragma unroll
      for (int t = 0; t < 8; ++t) {
        p0[t] += __uint_as_float(zA[t] << 16);
        p1[t] += __uint_as_float(zA[t] & 0xffff0000u);
      }
    };
    auto consB = [&]() {
#pragma unroll
      for (int t = 0; t < 8; ++t) {
        p0[t] += __uint_as_float(zB[t] << 16);
        p1[t] += __uint_as_float(zB[t] & 0xffff0000u);
      }
    };
    loadA(0);
    int g = 0;
    for (; g + 2 <= ng; g += 2) {
      loadB(g + 1);
      consA();
      if (g + 2 < ng) loadA(g + 2);
      consB();
    }
    if (g < ng) consA();
  }
  float a0 = ((p0[0] + p0[1]) + (p0[2] + p0[3])) + ((p0[4] + p0[5]) + (p0[6] + p0[7]));
  float a1 = ((p1[0] + p1[1]) + (p1[2] + p1[3])) + ((p1[4] + p1[5]) + (p1[6] + p1[7]));
  a0 = fmaxf(a0, 0.f);
  a1 = fmaxf(a1, 0.f);
  uint_t outp = (uint_t)f2bf(a0) | ((uint_t)f2bf(a1) << 16);
  if (lane >= 50) outp = 0u;  // pad cols 100..127 = 0
  *(uint_t*)(H + (size_t)node * 128 + lane * 2) = outp;
}

// ---------------- D7-10: fused gather-first + GEMM (R3-verified, R6 pipelined gather) ----------

__global__ __launch_bounds__(512) void fused_layer(
    const ushort_t* __restrict__ Hin,
    const ushort_t* __restrict__ Wf,    // [128][256] bf16
    const float* __restrict__ bias,     // [100]
    const int* __restrict__ offs, const int* __restrict__ csr,
    ushort_t* __restrict__ Hout) {
  __shared__ short alds[16 * AST];

  int tid = threadIdx.x;
  int w = tid >> 6, lane = tid & 63, q = lane >> 4, m16 = lane & 15;
  int tile = blockIdx.x;

  bf16x8 wreg[8];
#pragma unroll
  for (int s = 0; s < 8; ++s)
    wreg[s] = *(const bf16x8*)(Wf + (size_t)(w * 16 + m16) * 256 + s * 32 + q * 8);
  int n0 = w * 16 + q * 4;
  float4 bb = make_float4(0.f, 0.f, 0.f, 0.f);
  if (n0 < 100) bb = *(const float4*)(bias + n0);

  int off = (lane < 50 ? lane : 49) * 2;
  for (int sub = 0; sub < 2; ++sub) {
    int row = w * 2 + sub;
    int node = tile * 16 + row;
    node = __builtin_amdgcn_readfirstlane(node);
    uint_t hv = *(const uint_t*)(Hin + (size_t)node * 128 + lane * 2);
    *(uint_t*)&alds[row * AST + 128 + lane * 2] = hv;   // own-h, A cols 128..255
    float p0[8], p1[8];
#pragma unroll
    for (int u = 0; u < 8; ++u) { p0[u] = 0.f; p1[u] = 0.f; }
    int s = offs[node], e = offs[node + 1];
    uint_t zA[8], zB[8];
    for (int j = s; j < e; j += 64) {
      int rem = e - j;
      int ng = (rem > 64 ? 64 : rem) >> 3;
      int vidx = csr[j + lane];
      auto loadA = [&](int g) {
#pragma unroll
        for (int t = 0; t < 8; ++t) {
          int idx = __builtin_amdgcn_readlane(vidx, g * 8 + t);
          zA[t] = *(const uint_t*)(Hin + (size_t)idx * 128 + off);
        }
      };
      auto loadB = [&](int g) {
#pragma unroll
        for (int t = 0; t < 8; ++t) {
          int idx = __builtin_amdgcn_readlane(vidx, g * 8 + t);
          zB[t] = *(const uint_t*)(Hin + (size_t)idx * 128 + off);
        }
      };
      auto consA = [&]() {
#pragma unroll
        for (int t = 0; t < 8; ++t) {
          p0[t] += __uint_as_float(zA[t] << 16);
          p1[t] += __uint_as_float(zA[t] & 0xffff0000u);
        }
      };
      auto consB = [&]() {
#pragma unroll
        for (int t = 0; t < 8; ++t) {
          p0[t] += __uint_as_float(zB[t] << 16);
          p1[t] += __uint_as_float(zB[t] & 0xffff0000u);
        }
      };
      loadA(0);
      int g = 0;
      for (; g + 2 <= ng; g += 2) {
        loadB(g + 1);
        consA();
        if (g + 2 < ng) loadA(g + 2);
        consB();
      }
      if (g < ng) consA();
    }
    float a0 = ((p0[0] + p0[1]) + (p0[2] + p0[3])) + ((p0[4] + p0[5]) + (p0[6] + p0[7]));
    float a1 = ((p1[0] + p1[1]) + (p1[2] + p1[3])) + ((p1[4] + p1[5]) + (p1[6] + p1[7]));
    uint_t outp = (uint_t)f2bf(a0) | ((uint_t)f2bf(a1) << 16);
    if (lane >= 50) outp = 0u;   // A cols 100..127 = 0
    *(uint_t*)&alds[row * AST + lane * 2] = outp;
  }
  __syncthreads();
  f32x4 acc = (f32x4)0.f;
#pragma unroll
  for (int s = 0; s < 8; ++s) {
    bf16x8 af = *(const bf16x8*)&alds[m16 * AST + s * 32 + q * 8];
    acc = __builtin_amdgcn_mfma_f32_16x16x32_bf16(wreg[s], af, acc, 0, 0, 0);
  }
  int nodeo = tile * 16 + m16;
  ushort4 v;
  v.x = f2bf(fmaxf(acc[0] + bb.x, 0.f));
  v.y = f2bf(fmaxf(acc[1] + bb.y, 0.f));
  v.z = f2bf(fmaxf(acc[2] + bb.z, 0.f));
  v.w = f2bf(fmaxf(acc[3] + bb.w, 0.f));
  *(ushort4*)(Hout + (size_t)nodeo * 128 + n0) = v;  // n0<128: pad cols get 0
}

// ---------------- D11: fused pool + MLP head ----------------

__global__ __launch_bounds__(1024) void pool_mlp(
    const ushort_t* __restrict__ H, const int* __restrict__ batch,
    const float* __restrict__ lw1, const float* __restrict__ lb1,
    const float* __restrict__ lw2, const float* __restrict__ lb2,
    const float* __restrict__ lw3, const float* __restrict__ lb3,
    float* __restrict__ out) {
  int g = blockIdx.x;
  int t = threadIdx.x;
  int lo = 0, hi = N_NODES;
  while (lo < hi) { int mid = (lo + hi) >> 1; if (batch[mid] < g) lo = mid + 1; else hi = mid; }
  int s = lo;
  hi = N_NODES;
  while (lo < hi) { int mid = (lo + hi) >> 1; if (batch[mid] <= g) lo = mid + 1; else hi = mid; }
  int e = lo;

  int row = t >> 6;      // 16 node-rows
  int lane = t & 63;
  int off = (lane < 50 ? lane : 49) * 2;
  float a0 = 0.f, a1 = 0.f;
  for (int n = s + row; n < e; n += 16) {
    uint_t z = *(const uint_t*)(H + (size_t)n * 128 + off);
    a0 += __uint_as_float(z << 16);
    a1 += __uint_as_float(z & 0xffff0000u);
  }
  __shared__ float sh[16][104];
  __shared__ float r0[F], r1[F], r2[F];
  if (lane < 50) { sh[row][lane * 2] = a0; sh[row][lane * 2 + 1] = a1; }
  __syncthreads();
  if (t < F) {
    float acc = 0.f;
#pragma unroll
    for (int r = 0; r < 16; ++r) acc += sh[r][t];
    int cnt = e - s;
    float d = (cnt > 0) ? (float)cnt : 1.f;
    r0[t] = acc / d;
  }
  __syncthreads();
  if (t < F) {
    float sv = lb1[t];
    for (int k = 0; k < F; ++k) sv += r0[k] * lw1[t * F + k];
    r1[t] = fmaxf(sv, 0.f);
  }
  __syncthreads();
  if (t < F) {
    float sv = lb2[t];
    for (int k = 0; k < F; ++k) sv += r1[k] * lw2[t * F + k];
    r2[t] = fmaxf(sv, 0.f);
  }
  __syncthreads();
  if (t < 29) {
    float sv = lb3[t];
    for (int k = 0; k < F; ++k) sv += r2[k] * lw3[t * F + k];
    out[g * 29 + t] = sv;
  }
}

// ---------------- launch ------------------------------------------------------------------------

extern "C" void kernel_launch(void* const* d_in, const int* in_sizes, int n_in,
                              void* d_out, int out_size, void* d_ws, size_t ws_size,
                              hipStream_t stream) {
  const float* x       = (const float*)d_in[0];
  const int*   ei      = (const int*)d_in[1];
  const int*   batch   = (const int*)d_in[2];
  const float* w1_rel  = (const float*)d_in[3];
  const float* w1_root = (const float*)d_in[4];
  const float* b1      = (const float*)d_in[5];
  const float* w_rel   = (const float*)d_in[6];
  const float* w_root  = (const float*)d_in[7];
  const float* bvec    = (const float*)d_in[8];
  const float* lw1     = (const float*)d_in[9];
  const float* lb1     = (const float*)d_in[10];
  const float* lw2     = (const float*)d_in[11];
  const float* lb2     = (const float*)d_in[12];
  const float* lw3     = (const float*)d_in[13];
  const float* lb3     = (const float*)d_in[14];
  float* out = (float*)d_out;

  // workspace layout (sentinel row at index N_NODES in H1/H2/ZP)
  char* ws = (char*)d_ws;
  size_t o = 0;
  auto alloc = [&](size_t bytes) { void* p = ws + o; o = (o + bytes + 511) & ~(size_t)511; return p; };
  ushort_t* H1   = (ushort_t*)alloc((size_t)(N_NODES + 1) * 128 * 2);
  ushort_t* H2   = (ushort_t*)alloc((size_t)(N_NODES + 1) * 128 * 2);
  ushort_t* ZP   = (ushort_t*)alloc((size_t)(N_NODES + 1) * 256 * 2);
  ushort_t* Wp1  = (ushort_t*)alloc((size_t)208 * 384 * 2);
  ushort_t* Wf   = (ushort_t*)alloc((size_t)4 * 128 * 256 * 2);
  int* cnt    = (int*)alloc((size_t)SCAN_PAD * 4);
  int* offs   = (int*)alloc((size_t)(N_NODES + 1) * 4);
  int* cursor = (int*)alloc((size_t)(N_NODES + 1) * 4);
  int* csr    = (int*)alloc((size_t)CSR_CAP * 4);

  const int E = N_EDGES;
  const int* srcv = ei;
  const int* dstv = ei + E;

  // 11 dispatches
  pack_all<<<1052, 256, 0, stream>>>(w1_rel, w1_root, w_rel, w_root, Wp1, Wf, cnt, csr, ZP, H1, H2);
  hist_kernel<<<HIST_BLOCKS, 256, 0, stream>>>(dstv, cnt, E);
  scan_all<<<1, 1024, 0, stream>>>(cnt, offs, cursor);
  fill_kernel<<<HIST_BLOCKS, 256, 0, stream>>>(srcv, dstv, cursor, csr, E);

  int mmgrid = (N_NODES + 63) / 64;  // 782
  conv_mfma<true><<<mmgrid, 256, 0, stream>>>(x, Wp1, b1, ZP, 384);
  gather_bf16<<<N_NODES / 4, 256, 0, stream>>>(ZP, offs, csr, H1);

  const ushort_t* hin = H1;
  ushort_t* hout = H2;
  for (int l = 0; l < 4; ++l) {
    fused_layer<<<N_NODES / 16, 512, 0, stream>>>(hin, Wf + (size_t)l * 128 * 256,
                                                  bvec + (size_t)l * F, offs, csr, hout);
    const ushort_t* tmp = hout; hout = (ushort_t*)hin; hin = tmp;
  }
  // after 4 swaps hin == H1
  pool_mlp<<<N_GRAPHS, 1024, 0, stream>>>(hin, batch, lw1, lb1, lw2, lb2, lw3, lb3, out);
}

// Round 7
// 462.443 us; speedup vs baseline: 1.4090x; 1.2458x over previous
//
#include <hip/hip_runtime.h>

#define N_NODES 50000
#define N_EDGES 800000
#define N_GRAPHS 256
#define F 100  // hidden dim

#define SCAN_B 512
#define SCAN_NB 98          // 98*512 = 50176 >= 50001
#define SCAN_PAD (SCAN_NB * SCAN_B)

#define PART_SZ 6250        // 8 dst partitions * 6250 = 50000
#define FILL_CHUNK 2048
#define HIST_BLOCKS 3128    // 391 chunks * 8 partitions

#define SROW 72             // conv1 LDS row stride in shorts
#define EPS 264             // conv1 epilogue LDS row stride in shorts
#define AST 264             // fused-layer A-tile row stride in shorts

#define SENT N_NODES        // sentinel row index (zeroed) for CSR padding
#define CSR_CAP 1155072     // 282*4096 ints >= 800000 + 50000*7 + 64 overread slack

typedef __attribute__((ext_vector_type(8))) short bf16x8;
typedef __attribute__((ext_vector_type(4))) float f32x4;
typedef unsigned short ushort_t;
typedef unsigned int uint_t;

__device__ inline ushort_t f2bf(float f) {  // RNE float->bf16
  uint_t u = __float_as_uint(f);
  uint_t r = (u + 0x7fffu + ((u >> 16) & 1u)) >> 16;
  return (ushort_t)r;
}

// ---------------- D1: merged packing + cnt zeroing + csr sentinel prefill ----------------

__global__ __launch_bounds__(256) void pack_all(
    const float* __restrict__ w1_rel, const float* __restrict__ w1_root,
    const float* __restrict__ w_rel, const float* __restrict__ w_root,
    ushort_t* __restrict__ Wp1, ushort_t* __restrict__ Wf, int* __restrict__ cnt,
    int* __restrict__ csr, ushort_t* __restrict__ ZP,
    ushort_t* __restrict__ H1, ushort_t* __restrict__ H2) {
  int b = blockIdx.x;
  int tid = threadIdx.x;
  if (b < 208) {
    int row = b;
    for (int k = tid; k < 384; k += 256) {
      float v = 0.f;
      if (k < 336) {
        if (row < 100) v = w1_rel[row * 336 + k];
        else if (row < 200) v = w1_root[(row - 100) * 336 + k];
      }
      Wp1[(size_t)row * 384 + k] = f2bf(v);
    }
  } else if (b < 720) {
    int rowl = b - 208;           // l*128 + row
    int l = rowl >> 7, row = rowl & 127;
    int k = tid;                  // 0..255
    float v = 0.f;
    if (row < 100) {
      if (k < 100) v = w_rel[((size_t)l * 100 + row) * 100 + k];
      else if (k >= 128 && k < 228) v = w_root[((size_t)l * 100 + row) * 100 + (k - 128)];
    }
    Wf[(size_t)rowl * 256 + k] = f2bf(v);
  } else if (b < 769) {
    int z = b - 720;              // 0..48, each zeroes 1024 ints
    *(int4*)(cnt + (size_t)z * 1024 + tid * 4) = make_int4(0, 0, 0, 0);
  } else if (b < 1051) {
    int i0 = (b - 769) * 4096 + tid * 16;
    int4 sv = make_int4(SENT, SENT, SENT, SENT);
    *(int4*)(csr + i0) = sv; *(int4*)(csr + i0 + 4) = sv;
    *(int4*)(csr + i0 + 8) = sv; *(int4*)(csr + i0 + 12) = sv;
  } else {
    uint4 z4 = make_uint4(0u, 0u, 0u, 0u);
    if (tid < 32)      *(uint4*)(ZP + (size_t)SENT * 256 + tid * 8) = z4;
    else if (tid < 48) *(uint4*)(H1 + (size_t)SENT * 128 + (tid - 32) * 8) = z4;
    else if (tid < 64) *(uint4*)(H2 + (size_t)SENT * 128 + (tid - 48) * 8) = z4;
  }
}

// ---------------- D2: hist ----------------

__global__ __launch_bounds__(256) void hist_kernel(const int* __restrict__ dst,
                                                   int* __restrict__ cnt, int E) {
  int part = blockIdx.x & 7;
  int lo = part * PART_SZ, hi = lo + PART_SZ;
  int base = (blockIdx.x >> 3) * FILL_CHUNK;
  int end = base + FILL_CHUNK; if (end > E) end = E;
  for (int i = base + threadIdx.x; i < end; i += 256) {
    int d = dst[i];
    if (d >= lo && d < hi) atomicAdd(&cnt[d], 1);
  }
}

// ---------------- D3-5: 3-phase parallel scan (R6 lesson: single-block scan = 95us on 1 CU;
// the 3-dispatch parallel form is ~12us total. Slots padded to multiples of 8.) ----------------

__global__ __launch_bounds__(SCAN_B) void scan1_kernel(const int* __restrict__ cnt,
                                                       int* __restrict__ excl,
                                                       int* __restrict__ bsum) {
  __shared__ int sh[SCAN_B];
  int t = threadIdx.x;
  int i = blockIdx.x * SCAN_B + t;
  int v = (cnt[i] + 7) & ~7;     // padded slot size
  sh[t] = v;
  __syncthreads();
  for (int off = 1; off < SCAN_B; off <<= 1) {
    int u = (t >= off) ? sh[t - off] : 0;
    __syncthreads();
    sh[t] += u;
    __syncthreads();
  }
  excl[i] = sh[t] - v;
  if (t == SCAN_B - 1) bsum[blockIdx.x] = sh[t];
}

__global__ __launch_bounds__(128) void scan2_kernel(int* __restrict__ bsum) {
  __shared__ int sh[128];
  int t = threadIdx.x;
  int v = (t < SCAN_NB) ? bsum[t] : 0;
  sh[t] = v;
  __syncthreads();
  for (int off = 1; off < 128; off <<= 1) {
    int u = (t >= off) ? sh[t - off] : 0;
    __syncthreads();
    sh[t] += u;
    __syncthreads();
  }
  if (t < SCAN_NB) bsum[t] = sh[t] - v;
}

__global__ __launch_bounds__(SCAN_B) void scan3_kernel(const int* __restrict__ excl,
                                                       const int* __restrict__ bsum,
                                                       int* __restrict__ offs,
                                                       int* __restrict__ cursor) {
  int i = blockIdx.x * SCAN_B + threadIdx.x;
  int v = excl[i] + bsum[blockIdx.x];
  if (i <= N_NODES) { offs[i] = v; cursor[i] = v; }
}

// ---------------- D6: fill (real edges into [offs, offs+cnt); pads stay SENT) ----------------

__global__ __launch_bounds__(256) void fill_kernel(const int* __restrict__ src,
                                                   const int* __restrict__ dst,
                                                   int* __restrict__ cursor,
                                                   int* __restrict__ csr_src, int E) {
  int part = blockIdx.x & 7;
  int lo = part * PART_SZ, hi = lo + PART_SZ;
  int base = (blockIdx.x >> 3) * FILL_CHUNK;
  int end = base + FILL_CHUNK; if (end > E) end = E;
  for (int i = base + threadIdx.x; i < end; i += 256) {
    int d = dst[i];
    if (d >= lo && d < hi) {
      int p = atomicAdd(&cursor[d], 1);
      csr_src[p] = src[i];
    }
  }
}

// ---------------- D7: layer-1 conv (R1-verified: LDS staging + LDS-transpose epilogue) ----------

template <bool AF32>
__global__ __launch_bounds__(256) void conv_mfma(
    const void* __restrict__ Aptr, const ushort_t* __restrict__ Wp,
    const float* __restrict__ bias,
    ushort_t* __restrict__ ZP, int Kp) {
  __shared__ short smem[64 * SROW + 208 * SROW];
  __shared__ float bias_s[104];
  short* alds = smem;
  short* blds = smem + 64 * SROW;

  int tid = threadIdx.x;
  int n0 = blockIdx.x * 64;
  if (tid < 100) bias_s[tid] = bias[tid];

  f32x4 acc[13];
#pragma unroll
  for (int b = 0; b < 13; ++b) acc[b] = (f32x4)0.f;

  int w = tid >> 6, lane = tid & 63, q = lane >> 4, m16 = lane & 15;

  int ar[2], aq[2];
#pragma unroll
  for (int u = 0; u < 2; ++u) { int c = tid + u * 256; ar[u] = c >> 3; aq[u] = c & 7; }

  bf16x8 areg[2], breg[7];

  auto load_chunk = [&](int k0) {
#pragma unroll
    for (int u = 0; u < 2; ++u) {
      int node = n0 + ar[u];
      int k = k0 + aq[u] * 8;
      bf16x8 val = (bf16x8)0;
      if (AF32) {
        if (node < N_NODES && k < 336) {
          const float* p = (const float*)Aptr + (size_t)node * 336 + k;
          float4 f0 = *(const float4*)p;
          float4 f1 = *(const float4*)(p + 4);
          val[0] = (short)f2bf(f0.x); val[1] = (short)f2bf(f0.y);
          val[2] = (short)f2bf(f0.z); val[3] = (short)f2bf(f0.w);
          val[4] = (short)f2bf(f1.x); val[5] = (short)f2bf(f1.y);
          val[6] = (short)f2bf(f1.z); val[7] = (short)f2bf(f1.w);
        }
      } else {
        if (node < N_NODES)
          val = *(const bf16x8*)((const short*)Aptr + (size_t)node * 128 + k);
      }
      areg[u] = val;
    }
#pragma unroll
    for (int u = 0; u < 7; ++u) {
      int c = tid + u * 256;
      if (c < 1664) {
        int r = c >> 3, qq = c & 7;
        breg[u] = *(const bf16x8*)((const short*)Wp + (size_t)r * Kp + k0 + qq * 8);
      }
    }
  };

  load_chunk(0);

  for (int k0 = 0; k0 < Kp; k0 += 64) {
#pragma unroll
    for (int u = 0; u < 2; ++u)
      *(bf16x8*)&alds[ar[u] * SROW + aq[u] * 8] = areg[u];
#pragma unroll
    for (int u = 0; u < 7; ++u) {
      int c = tid + u * 256;
      if (c < 1664) {
        int r = c >> 3, qq = c & 7;
        *(bf16x8*)&blds[r * SROW + qq * 8] = breg[u];
      }
    }
    __syncthreads();
    if (k0 + 64 < Kp) load_chunk(k0 + 64);
#pragma unroll
    for (int s = 0; s < 2; ++s) {
      bf16x8 a = *(const bf16x8*)&alds[(w * 16 + m16) * SROW + s * 32 + q * 8];
#pragma unroll
      for (int b = 0; b < 13; ++b) {
        bf16x8 bf = *(const bf16x8*)&blds[(b * 16 + m16) * SROW + s * 32 + q * 8];
        acc[b] = __builtin_amdgcn_mfma_f32_16x16x32_bf16(a, bf, acc[b], 0, 0, 0);
      }
    }
    __syncthreads();
  }

  // epilogue: transpose through LDS, full-line coalesced stores
  short* ep = smem;
#pragma unroll
  for (int b = 0; b < 13; ++b) {
    int n = b * 16 + m16;
    if (n < 200) {
      int c = (n < 100) ? n : (n + 28);
      float add = (n < 100) ? 0.f : bias_s[(n - 100) & 127];
#pragma unroll
      for (int r = 0; r < 4; ++r) {
        int row = w * 16 + q * 4 + r;
        ep[row * EPS + c] = (short)f2bf(acc[b][r] + add);
      }
    }
  }
  __syncthreads();
#pragma unroll
  for (int j = 0; j < 8; ++j) {
    int i = tid + j * 256;
    int row = i >> 5, c16 = i & 31;
    int node = n0 + row;
    if (node < N_NODES) {
      *(uint4*)(ZP + (size_t)node * 256 + c16 * 8) =
          *(const uint4*)&ep[row * EPS + c16 * 8];
    }
  }
}

// ---------------- D8: gather1 — R7: TWO independent nodes per wave, interleaved chains ----------
// Per-node serial depth (offs->csr->rows) was the bottleneck; interleaving two nodes doubles
// loads in flight per wave (up to 32). Fast path covers deg<=64 (true for this graph);
// sequential fallback keeps correctness for any degree.

__global__ __launch_bounds__(256) void gather_bf16(
    const ushort_t* __restrict__ ZP,
    const int* __restrict__ offs, const int* __restrict__ csr,
    ushort_t* __restrict__ H) {
  int lane = threadIdx.x & 63;
  int off = (lane < 50 ? lane : 49) * 2;
  int wid = threadIdx.x >> 6;
  int nA = __builtin_amdgcn_readfirstlane(blockIdx.x * 8 + wid * 2);
  int nB = nA + 1;

  uint_t zrA = *(const uint_t*)(ZP + (size_t)nA * 256 + 128 + off);  // Zroot halves
  uint_t zrB = *(const uint_t*)(ZP + (size_t)nB * 256 + 128 + off);

  int sA = offs[nA], sB = offs[nA + 1], eB = offs[nA + 2];
  int eA = sB;

  float pA0[8], pA1[8], pB0[8], pB1[8];
#pragma unroll
  for (int u = 0; u < 8; ++u) { pA0[u] = 0.f; pA1[u] = 0.f; pB0[u] = 0.f; pB1[u] = 0.f; }
  pA0[0] = __uint_as_float(zrA << 16);
  pA1[0] = __uint_as_float(zrA & 0xffff0000u);
  pB0[0] = __uint_as_float(zrB << 16);
  pB1[0] = __uint_as_float(zrB & 0xffff0000u);

  uint_t bA0[8], bA1[8], bB0[8], bB1[8];
  auto LD = [&](uint_t (&buf)[8], int vidx, int g) {
#pragma unroll
    for (int t = 0; t < 8; ++t) {
      int idx = __builtin_amdgcn_readlane(vidx, g * 8 + t);
      buf[t] = *(const uint_t*)(ZP + (size_t)idx * 256 + off);
    }
  };
  auto CS = [&](uint_t (&buf)[8], float (&p0)[8], float (&p1)[8]) {
#pragma unroll
    for (int t = 0; t < 8; ++t) {
      p0[t] += __uint_as_float(buf[t] << 16);
      p1[t] += __uint_as_float(buf[t] & 0xffff0000u);
    }
  };

  if (eA - sA <= 64 && eB - sB <= 64) {
    int ngA = (eA - sA) >> 3, ngB = (eB - sB) >> 3;
    int vA = csr[sA + lane];
    int vB = csr[sB + lane];
    if (ngA > 0) LD(bA0, vA, 0);
    if (ngB > 0) LD(bB0, vB, 0);
    int ngM = ngA > ngB ? ngA : ngB;
    for (int g = 0; g < ngM; g += 2) {
      if (g + 1 < ngA) LD(bA1, vA, g + 1);
      if (g + 1 < ngB) LD(bB1, vB, g + 1);
      if (g < ngA) CS(bA0, pA0, pA1);
      if (g < ngB) CS(bB0, pB0, pB1);
      if (g + 2 < ngA) LD(bA0, vA, g + 2);
      if (g + 2 < ngB) LD(bB0, vB, g + 2);
      if (g + 1 < ngA) CS(bA1, pA0, pA1);
      if (g + 1 < ngB) CS(bB1, pB0, pB1);
    }
  } else {
    auto seq = [&](int s, int e, float (&p0)[8], float (&p1)[8]) {
      for (int j = s; j < e; j += 64) {
        int rem = e - j;
        int ng = (rem > 64 ? 64 : rem) >> 3;
        int v = csr[j + lane];
        for (int g = 0; g < ng; ++g) { LD(bA0, v, g); CS(bA0, p0, p1); }
      }
    };
    seq(sA, eA, pA0, pA1);
    seq(sB, eB, pB0, pB1);
  }

  float a0 = ((pA0[0] + pA0[1]) + (pA0[2] + pA0[3])) + ((pA0[4] + pA0[5]) + (pA0[6] + pA0[7]));
  float a1 = ((pA1[0] + pA1[1]) + (pA1[2] + pA1[3])) + ((pA1[4] + pA1[5]) + (pA1[6] + pA1[7]));
  float b0 = ((pB0[0] + pB0[1]) + (pB0[2] + pB0[3])) + ((pB0[4] + pB0[5]) + (pB0[6] + pB0[7]));
  float b1 = ((pB1[0] + pB1[1]) + (pB1[2] + pB1[3])) + ((pB1[4] + pB1[5]) + (pB1[6] + pB1[7]));
  uint_t outA = (uint_t)f2bf(fmaxf(a0, 0.f)) | ((uint_t)f2bf(fmaxf(a1, 0.f)) << 16);
  uint_t outB = (uint_t)f2bf(fmaxf(b0, 0.f)) | ((uint_t)f2bf(fmaxf(b1, 0.f)) << 16);
  if (lane >= 50) { outA = 0u; outB = 0u; }  // pad cols 100..127 = 0
  *(uint_t*)(H + (size_t)nA * 128 + lane * 2) = outA;
  *(uint_t*)(H + (size_t)nB * 128 + lane * 2) = outB;
}

// ---------------- D9-12: fused gather-first + GEMM — R7 interleaved dual-row gather ----------

__global__ __launch_bounds__(512) void fused_layer(
    const ushort_t* __restrict__ Hin,
    const ushort_t* __restrict__ Wf,    // [128][256] bf16
    const float* __restrict__ bias,     // [100]
    const int* __restrict__ offs, const int* __restrict__ csr,
    ushort_t* __restrict__ Hout) {
  __shared__ short alds[16 * AST];

  int tid = threadIdx.x;
  int w = tid >> 6, lane = tid & 63, q = lane >> 4, m16 = lane & 15;
  int tile = blockIdx.x;
  int off = (lane < 50 ? lane : 49) * 2;

  int rowA = w * 2, rowB = w * 2 + 1;
  int nA = __builtin_amdgcn_readfirstlane(tile * 16 + rowA);
  int nB = nA + 1;

  // own-h copies (A cols 128..255) — issue early, store to LDS
  uint_t hvA = *(const uint_t*)(Hin + (size_t)nA * 128 + lane * 2);
  uint_t hvB = *(const uint_t*)(Hin + (size_t)nB * 128 + lane * 2);
  *(uint_t*)&alds[rowA * AST + 128 + lane * 2] = hvA;
  *(uint_t*)&alds[rowB * AST + 128 + lane * 2] = hvB;

  int sA = offs[nA], sB = offs[nA + 1], eB = offs[nA + 2];
  int eA = sB;

  float pA0[8], pA1[8], pB0[8], pB1[8];
#pragma unroll
  for (int u = 0; u < 8; ++u) { pA0[u] = 0.f; pA1[u] = 0.f; pB0[u] = 0.f; pB1[u] = 0.f; }

  uint_t bA0[8], bA1[8], bB0[8], bB1[8];
  auto LD = [&](uint_t (&buf)[8], int vidx, int g) {
#pragma unroll
    for (int t = 0; t < 8; ++t) {
      int idx = __builtin_amdgcn_readlane(vidx, g * 8 + t);
      buf[t] = *(const uint_t*)(Hin + (size_t)idx * 128 + off);
    }
  };
  auto CS = [&](uint_t (&buf)[8], float (&p0)[8], float (&p1)[8]) {
#pragma unroll
    for (int t = 0; t < 8; ++t) {
      p0[t] += __uint_as_float(buf[t] << 16);
      p1[t] += __uint_as_float(buf[t] & 0xffff0000u);
    }
  };

  if (eA - sA <= 64 && eB - sB <= 64) {
    int ngA = (eA - sA) >> 3, ngB = (eB - sB) >> 3;
    int vA = csr[sA + lane];
    int vB = csr[sB + lane];
    if (ngA > 0) LD(bA0, vA, 0);
    if (ngB > 0) LD(bB0, vB, 0);
    int ngM = ngA > ngB ? ngA : ngB;
    for (int g = 0; g < ngM; g += 2) {
      if (g + 1 < ngA) LD(bA1, vA, g + 1);
      if (g + 1 < ngB) LD(bB1, vB, g + 1);
      if (g < ngA) CS(bA0, pA0, pA1);
      if (g < ngB) CS(bB0, pB0, pB1);
      if (g + 2 < ngA) LD(bA0, vA, g + 2);
      if (g + 2 < ngB) LD(bB0, vB, g + 2);
      if (g + 1 < ngA) CS(bA1, pA0, pA1);
      if (g + 1 < ngB) CS(bB1, pB0, pB1);
    }
  } else {
    auto seq = [&](int s, int e, float (&p0)[8], float (&p1)[8]) {
      for (int j = s; j < e; j += 64) {
        int rem = e - j;
        int ng = (rem > 64 ? 64 : rem) >> 3;
        int v = csr[j + lane];
        for (int g = 0; g < ng; ++g) { LD(bA0, v, g); CS(bA0, p0, p1); }
      }
    };
    seq(sA, eA, pA0, pA1);
    seq(sB, eB, pB0, pB1);
  }

  float a0 = ((pA0[0] + pA0[1]) + (pA0[2] + pA0[3])) + ((pA0[4] + pA0[5]) + (pA0[6] + pA0[7]));
  float a1 = ((pA1[0] + pA1[1]) + (pA1[2] + pA1[3])) + ((pA1[4] + pA1[5]) + (pA1[6] + pA1[7]));
  float c0 = ((pB0[0] + pB0[1]) + (pB0[2] + pB0[3])) + ((pB0[4] + pB0[5]) + (pB0[6] + pB0[7]));
  float c1 = ((pB1[0] + pB1[1]) + (pB1[2] + pB1[3])) + ((pB1[4] + pB1[5]) + (pB1[6] + pB1[7]));
  uint_t outA = (uint_t)f2bf(a0) | ((uint_t)f2bf(a1) << 16);
  uint_t outB = (uint_t)f2bf(c0) | ((uint_t)f2bf(c1) << 16);
  if (lane >= 50) { outA = 0u; outB = 0u; }   // A cols 100..127 = 0
  *(uint_t*)&alds[rowA * AST + lane * 2] = outA;
  *(uint_t*)&alds[rowB * AST + lane * 2] = outB;

  // W frag b=w into regs (post-gather: keeps gather-phase VGPR pressure low)
  bf16x8 wreg[8];
#pragma unroll
  for (int s = 0; s < 8; ++s)
    wreg[s] = *(const bf16x8*)(Wf + (size_t)(w * 16 + m16) * 256 + s * 32 + q * 8);
  int n0 = w * 16 + q * 4;
  float4 bb = make_float4(0.f, 0.f, 0.f, 0.f);
  if (n0 < 100) bb = *(const float4*)(bias + n0);

  __syncthreads();
  f32x4 acc = (f32x4)0.f;
#pragma unroll
  for (int s = 0; s < 8; ++s) {
    bf16x8 af = *(const bf16x8*)&alds[m16 * AST + s * 32 + q * 8];
    acc = __builtin_amdgcn_mfma_f32_16x16x32_bf16(wreg[s], af, acc, 0, 0, 0);
  }
  int nodeo = tile * 16 + m16;
  ushort4 v;
  v.x = f2bf(fmaxf(acc[0] + bb.x, 0.f));
  v.y = f2bf(fmaxf(acc[1] + bb.y, 0.f));
  v.z = f2bf(fmaxf(acc[2] + bb.z, 0.f));
  v.w = f2bf(fmaxf(acc[3] + bb.w, 0.f));
  *(ushort4*)(Hout + (size_t)nodeo * 128 + n0) = v;  // n0<128: pad cols get 0
}

// ---------------- D13: fused pool + MLP head ----------------

__global__ __launch_bounds__(1024) void pool_mlp(
    const ushort_t* __restrict__ H, const int* __restrict__ batch,
    const float* __restrict__ lw1, const float* __restrict__ lb1,
    const float* __restrict__ lw2, const float* __restrict__ lb2,
    const float* __restrict__ lw3, const float* __restrict__ lb3,
    float* __restrict__ out) {
  int g = blockIdx.x;
  int t = threadIdx.x;
  int lo = 0, hi = N_NODES;
  while (lo < hi) { int mid = (lo + hi) >> 1; if (batch[mid] < g) lo = mid + 1; else hi = mid; }
  int s = lo;
  hi = N_NODES;
  while (lo < hi) { int mid = (lo + hi) >> 1; if (batch[mid] <= g) lo = mid + 1; else hi = mid; }
  int e = lo;

  int row = t >> 6;      // 16 node-rows
  int lane = t & 63;
  int off = (lane < 50 ? lane : 49) * 2;
  float a0 = 0.f, a1 = 0.f;
  for (int n = s + row; n < e; n += 16) {
    uint_t z = *(const uint_t*)(H + (size_t)n * 128 + off);
    a0 += __uint_as_float(z << 16);
    a1 += __uint_as_float(z & 0xffff0000u);
  }
  __shared__ float sh[16][104];
  __shared__ float r0[F], r1[F], r2[F];
  if (lane < 50) { sh[row][lane * 2] = a0; sh[row][lane * 2 + 1] = a1; }
  __syncthreads();
  if (t < F) {
    float acc = 0.f;
#pragma unroll
    for (int r = 0; r < 16; ++r) acc += sh[r][t];
    int cnt = e - s;
    float d = (cnt > 0) ? (float)cnt : 1.f;
    r0[t] = acc / d;
  }
  __syncthreads();
  if (t < F) {
    float sv = lb1[t];
    for (int k = 0; k < F; ++k) sv += r0[k] * lw1[t * F + k];
    r1[t] = fmaxf(sv, 0.f);
  }
  __syncthreads();
  if (t < F) {
    float sv = lb2[t];
    for (int k = 0; k < F; ++k) sv += r1[k] * lw2[t * F + k];
    r2[t] = fmaxf(sv, 0.f);
  }
  __syncthreads();
  if (t < 29) {
    float sv = lb3[t];
    for (int k = 0; k < F; ++k) sv += r2[k] * lw3[t * F + k];
    out[g * 29 + t] = sv;
  }
}

// ---------------- launch ------------------------------------------------------------------------

extern "C" void kernel_launch(void* const* d_in, const int* in_sizes, int n_in,
                              void* d_out, int out_size, void* d_ws, size_t ws_size,
                              hipStream_t stream) {
  const float* x       = (const float*)d_in[0];
  const int*   ei      = (const int*)d_in[1];
  const int*   batch   = (const int*)d_in[2];
  const float* w1_rel  = (const float*)d_in[3];
  const float* w1_root = (const float*)d_in[4];
  const float* b1      = (const float*)d_in[5];
  const float* w_rel   = (const float*)d_in[6];
  const float* w_root  = (const float*)d_in[7];
  const float* bvec    = (const float*)d_in[8];
  const float* lw1     = (const float*)d_in[9];
  const float* lb1     = (const float*)d_in[10];
  const float* lw2     = (const float*)d_in[11];
  const float* lb2     = (const float*)d_in[12];
  const float* lw3     = (const float*)d_in[13];
  const float* lb3     = (const float*)d_in[14];
  float* out = (float*)d_out;

  // workspace layout (sentinel row at index N_NODES in H1/H2/ZP)
  char* ws = (char*)d_ws;
  size_t o = 0;
  auto alloc = [&](size_t bytes) { void* p = ws + o; o = (o + bytes + 511) & ~(size_t)511; return p; };
  ushort_t* H1   = (ushort_t*)alloc((size_t)(N_NODES + 1) * 128 * 2);
  ushort_t* H2   = (ushort_t*)alloc((size_t)(N_NODES + 1) * 128 * 2);
  ushort_t* ZP   = (ushort_t*)alloc((size_t)(N_NODES + 1) * 256 * 2);
  ushort_t* Wp1  = (ushort_t*)alloc((size_t)208 * 384 * 2);
  ushort_t* Wf   = (ushort_t*)alloc((size_t)4 * 128 * 256 * 2);
  int* cnt    = (int*)alloc((size_t)SCAN_PAD * 4);
  int* excl   = (int*)alloc((size_t)SCAN_PAD * 4);
  int* bsum   = (int*)alloc((size_t)128 * 4);
  int* offs   = (int*)alloc((size_t)(N_NODES + 1) * 4);
  int* cursor = (int*)alloc((size_t)(N_NODES + 1) * 4);
  int* csr    = (int*)alloc((size_t)CSR_CAP * 4);

  const int E = N_EDGES;
  const int* srcv = ei;
  const int* dstv = ei + E;

  pack_all<<<1052, 256, 0, stream>>>(w1_rel, w1_root, w_rel, w_root, Wp1, Wf, cnt, csr, ZP, H1, H2);
  hist_kernel<<<HIST_BLOCKS, 256, 0, stream>>>(dstv, cnt, E);
  scan1_kernel<<<SCAN_NB, SCAN_B, 0, stream>>>(cnt, excl, bsum);
  scan2_kernel<<<1, 128, 0, stream>>>(bsum);
  scan3_kernel<<<SCAN_NB, SCAN_B, 0, stream>>>(excl, bsum, offs, cursor);
  fill_kernel<<<HIST_BLOCKS, 256, 0, stream>>>(srcv, dstv, cursor, csr, E);

  int mmgrid = (N_NODES + 63) / 64;  // 782
  conv_mfma<true><<<mmgrid, 256, 0, stream>>>(x, Wp1, b1, ZP, 384);
  gather_bf16<<<N_NODES / 8, 256, 0, stream>>>(ZP, offs, csr, H1);

  const ushort_t* hin = H1;
  ushort_t* hout = H2;
  for (int l = 0; l < 4; ++l) {
    fused_layer<<<N_NODES / 16, 512, 0, stream>>>(hin, Wf + (size_t)l * 128 * 256,
                                                  bvec + (size_t)l * F, offs, csr, hout);
    const ushort_t* tmp = hout; hout = (ushort_t*)hin; hin = tmp;
  }
  // after 4 swaps hin == H1
  pool_mlp<<<N_GRAPHS, 1024, 0, stream>>>(hin, batch, lw1, lb1, lw2, lb2, lw3, lb3, out);
}